// Round 2
// baseline (794.445 us; speedup 1.0000x reference)
//
#include <hip/hip_runtime.h>
#include <hip/hip_bf16.h>
#include <stdint.h>

#define N_PTS 500000
#define NVOX  65536

typedef __attribute__((ext_vector_type(8))) short bf16x8;   // 8 x bf16 (4 VGPRs)
typedef __attribute__((ext_vector_type(4))) float f32x4;    // MFMA accumulator

__device__ inline unsigned short f2bf(float f) {
    union { float f; unsigned int u; } v; v.f = f;
    unsigned int r = v.u + 0x7FFFu + ((v.u >> 16) & 1u);   // RNE
    return (unsigned short)(r >> 16);
}

// transpose [K][Nn] fp32 -> [Nn][K] bf16  (so B-fragments read contiguous along k)
__global__ void prep_wT(const float* __restrict__ src, unsigned short* __restrict__ dst,
                        int K, int Nn) {
    int i = blockIdx.x * 256 + threadIdx.x;
    if (i >= K * Nn) return;
    int n = i / K, k = i % K;
    dst[i] = f2bf(src[k * Nn + n]);
}

// W1 [6][64] -> [64][32] bf16, zero-padded in k (MFMA needs K=32)
__global__ void prep_w1T(const float* __restrict__ src, unsigned short* __restrict__ dst) {
    int i = blockIdx.x * 256 + threadIdx.x;
    if (i >= 64 * 32) return;
    int n = i >> 5, k = i & 31;
    dst[i] = (k < 6) ? f2bf(src[k * 64 + n]) : (unsigned short)0;
}

// ---------------------------------------------------------------------------
// K1: per 256-point tile: feat1 = relu(x@W1+b1) via MFMA (K padded to 32),
//     feat2 = relu(feat1@W2+b2) via MFMA; atomicMax(feat2) -> vox1acc.
// (feat2 is NOT stored to global; k3 recomputes it — keeps workspace small.)
// ---------------------------------------------------------------------------
__global__ __launch_bounds__(256) void k1_points(
    const float* __restrict__ inp, const int* __restrict__ idx,
    const unsigned short* __restrict__ W1T,  // [64][32] bf16
    const float* __restrict__ b1,
    const unsigned short* __restrict__ W2T,  // [128][64] bf16
    const float* __restrict__ b2,
    unsigned int* __restrict__ vox1acc)      // [V][128] fp32-as-uint (zeroed)
{
    __shared__ __align__(16) char sA[256 * 128];
    __shared__ float sb1[64];
    __shared__ float sb2[128];
    __shared__ int   sidx[256];
    const f32x4 fzero = {0.f, 0.f, 0.f, 0.f};
    int tid = threadIdx.x;
    int pbase = blockIdx.x * 256;
    if (tid < 64)  sb1[tid] = b1[tid];
    if (tid < 128) sb2[tid] = b2[tid];
    {
        int pt = pbase + tid;
        sidx[tid] = (pt < N_PTS) ? idx[pt] : 0;
        uint4 g0 = {0u, 0u, 0u, 0u};
        if (pt < N_PTS) {
            const float* x = inp + (size_t)pt * 6;
            g0.x = (unsigned)f2bf(x[0]) | ((unsigned)f2bf(x[1]) << 16);
            g0.y = (unsigned)f2bf(x[2]) | ((unsigned)f2bf(x[3]) << 16);
            g0.z = (unsigned)f2bf(x[4]) | ((unsigned)f2bf(x[5]) << 16);
        }
        int swz = (tid & 7) << 4;
        char* row = sA + tid * 128;
        uint4 z = {0u, 0u, 0u, 0u};
        *(uint4*)(row + (0  ^ swz)) = g0;
        *(uint4*)(row + (16 ^ swz)) = z;
        *(uint4*)(row + (32 ^ swz)) = z;
        *(uint4*)(row + (48 ^ swz)) = z;
    }
    __syncthreads();
    int wave = tid >> 6, lane = tid & 63, quad = lane >> 4, l16 = lane & 15;
    int mb = wave * 64;   // each wave owns 64 points (4 m-tiles)

    f32x4 acc[4][4];
    #pragma unroll
    for (int j = 0; j < 4; j++)
        #pragma unroll
        for (int mt = 0; mt < 4; mt++) acc[j][mt] = fzero;

    // GEMM1: [256][32] @ [32][64]
    {
        bf16x8 a[4];
        #pragma unroll
        for (int mt = 0; mt < 4; mt++) {
            int m = mb + mt * 16 + l16;
            a[mt] = *(const bf16x8*)(sA + m * 128 + ((quad * 16) ^ ((m & 7) << 4)));
        }
        #pragma unroll
        for (int j = 0; j < 4; j++) {
            int n = j * 16 + l16;
            bf16x8 b = *(const bf16x8*)(W1T + n * 32 + quad * 8);
            #pragma unroll
            for (int mt = 0; mt < 4; mt++)
                acc[j][mt] = __builtin_amdgcn_mfma_f32_16x16x32_bf16(a[mt], b, acc[j][mt], 0, 0, 0);
        }
    }
    __syncthreads();
    // feat1 (bias+relu) back into sA as [256][64] bf16, same swizzle
    #pragma unroll
    for (int j = 0; j < 4; j++) {
        int n = j * 16 + l16;
        float bias = sb1[n];
        #pragma unroll
        for (int mt = 0; mt < 4; mt++)
            #pragma unroll
            for (int r = 0; r < 4; r++) {
                int m = mb + mt * 16 + quad * 4 + r;
                float v = fmaxf(acc[j][mt][r] + bias, 0.f);
                *(unsigned short*)(sA + m * 128 + ((2 * n) ^ ((m & 7) << 4))) = f2bf(v);
            }
    }
    __syncthreads();
    // GEMM2: [256][64] @ [64][128], two passes of 4 n-tiles (reg pressure)
    #pragma unroll 1
    for (int pass = 0; pass < 2; pass++) {
        #pragma unroll
        for (int j = 0; j < 4; j++)
            #pragma unroll
            for (int mt = 0; mt < 4; mt++) acc[j][mt] = fzero;
        #pragma unroll
        for (int kt = 0; kt < 2; kt++) {
            bf16x8 a[4];
            #pragma unroll
            for (int mt = 0; mt < 4; mt++) {
                int m = mb + mt * 16 + l16;
                a[mt] = *(const bf16x8*)(sA + m * 128 + ((kt * 64 + quad * 16) ^ ((m & 7) << 4)));
            }
            #pragma unroll
            for (int j = 0; j < 4; j++) {
                int n = (pass * 4 + j) * 16 + l16;
                bf16x8 b = *(const bf16x8*)(W2T + n * 64 + kt * 32 + quad * 8);
                #pragma unroll
                for (int mt = 0; mt < 4; mt++)
                    acc[j][mt] = __builtin_amdgcn_mfma_f32_16x16x32_bf16(a[mt], b, acc[j][mt], 0, 0, 0);
            }
        }
        #pragma unroll
        for (int j = 0; j < 4; j++) {
            int n = (pass * 4 + j) * 16 + l16;
            float bias = sb2[n];
            #pragma unroll
            for (int mt = 0; mt < 4; mt++)
                #pragma unroll
                for (int r = 0; r < 4; r++) {
                    int m = mb + mt * 16 + quad * 4 + r;
                    int pt = pbase + m;
                    if (pt < N_PTS) {
                        float v = fmaxf(acc[j][mt][r] + bias, 0.f);
                        atomicMax(vox1acc + (size_t)sidx[m] * 128 + n,
                                  __float_as_uint(v) & 0x7fffffffu);
                    }
                }
        }
    }
}

// ---------------------------------------------------------------------------
// K3: per 64-point tile:
//   recompute feat1 = relu(x@W1+b1), feat2 = relu(feat1@W2+b2)  (small GEMMs)
//   A = [gather(vox1out, idx) | feat2]  (256 k, bf16, LDS, swizzled)
//   feat4 = relu(A@W3+b3) -> LDS (A-layout), feat5 = relu(feat4@W4+b4)
//   atomicMax(feat5) -> vox2acc (= d_out).   B-fragments straight from global.
// ---------------------------------------------------------------------------
__global__ __launch_bounds__(256) void k3_heavy(
    const float* __restrict__ inp, const int* __restrict__ idx,
    const unsigned short* __restrict__ W1T, const float* __restrict__ b1,
    const unsigned short* __restrict__ W2T, const float* __restrict__ b2,
    const unsigned short* __restrict__ vox1out,  // [V][128] bf16
    const unsigned short* __restrict__ W3T, const float* __restrict__ b3,
    const unsigned short* __restrict__ W4T, const float* __restrict__ b4,
    unsigned int* __restrict__ vox2acc)          // [V][256] fp32-as-uint (zeroed)
{
    __shared__ __align__(16) char sA[64 * 512];   // [64][256] bf16 concat / feat4
    __shared__ __align__(16) char sF1[64 * 128];  // [64][64]  bf16 feat1
    __shared__ __align__(16) char sIn[64 * 64];   // [64][32]  bf16 input (padded)
    __shared__ float sb1v[64];
    __shared__ float sb2v[128];
    __shared__ float sb3[256];
    __shared__ float sb4[256];
    __shared__ int   sidx[64];
    const f32x4 fzero = {0.f, 0.f, 0.f, 0.f};
    int tid = threadIdx.x;
    int pbase = blockIdx.x * 64;
    sb3[tid] = b3[tid];
    sb4[tid] = b4[tid];
    if (tid < 64)  sb1v[tid] = b1[tid];
    if (tid < 128) sb2v[tid] = b2[tid];
    if (tid < 64) {
        int pt = pbase + tid;
        sidx[tid] = (pt < N_PTS) ? idx[pt] : 0;
        uint4 g0 = {0u, 0u, 0u, 0u};
        if (pt < N_PTS) {
            const float* x = inp + (size_t)pt * 6;
            g0.x = (unsigned)f2bf(x[0]) | ((unsigned)f2bf(x[1]) << 16);
            g0.y = (unsigned)f2bf(x[2]) | ((unsigned)f2bf(x[3]) << 16);
            g0.z = (unsigned)f2bf(x[4]) | ((unsigned)f2bf(x[5]) << 16);
        }
        int swz2 = (tid & 3) << 4;
        char* row = sIn + tid * 64;
        uint4 z = {0u, 0u, 0u, 0u};
        *(uint4*)(row + (0  ^ swz2)) = g0;
        *(uint4*)(row + (16 ^ swz2)) = z;
        *(uint4*)(row + (32 ^ swz2)) = z;
        *(uint4*)(row + (48 ^ swz2)) = z;
    }
    __syncthreads();
    int wave = tid >> 6, lane = tid & 63, quad = lane >> 4, l16 = lane & 15;

    // issue the voxel-feature gather loads EARLY (latency hidden behind small GEMMs)
    uint4 g[4];
    #pragma unroll
    for (int it = 0; it < 4; it++) {
        int i = tid + 256 * it;
        int m = i >> 4, c = i & 15;
        uint4 val = {0u, 0u, 0u, 0u};
        if (pbase + m < N_PTS)
            val = ((const uint4*)(vox1out + (size_t)sidx[m] * 128))[c];
        g[it] = val;
    }

    // small GEMM1: feat1 = relu([64][32] @ [32][64] + b1); wave w owns n-tile w
    {
        f32x4 acc1[4];
        #pragma unroll
        for (int mt = 0; mt < 4; mt++) acc1[mt] = fzero;
        bf16x8 a[4];
        #pragma unroll
        for (int mt = 0; mt < 4; mt++) {
            int m = mt * 16 + l16;
            a[mt] = *(const bf16x8*)(sIn + m * 64 + ((quad * 16) ^ ((m & 3) << 4)));
        }
        int n = wave * 16 + l16;
        bf16x8 b = *(const bf16x8*)(W1T + n * 32 + quad * 8);
        #pragma unroll
        for (int mt = 0; mt < 4; mt++)
            acc1[mt] = __builtin_amdgcn_mfma_f32_16x16x32_bf16(a[mt], b, acc1[mt], 0, 0, 0);
        float bias = sb1v[n];
        #pragma unroll
        for (int mt = 0; mt < 4; mt++)
            #pragma unroll
            for (int r = 0; r < 4; r++) {
                int m = mt * 16 + quad * 4 + r;
                float v = fmaxf(acc1[mt][r] + bias, 0.f);
                *(unsigned short*)(sF1 + m * 128 + ((2 * n) ^ ((m & 7) << 4))) = f2bf(v);
            }
    }
    __syncthreads();
    // small GEMM2: feat2 = relu([64][64] @ [64][128] + b2); wave w owns n-tiles 2w,2w+1
    {
        f32x4 acc2[2][4];
        #pragma unroll
        for (int j = 0; j < 2; j++)
            #pragma unroll
            for (int mt = 0; mt < 4; mt++) acc2[j][mt] = fzero;
        #pragma unroll
        for (int kt = 0; kt < 2; kt++) {
            bf16x8 a[4];
            #pragma unroll
            for (int mt = 0; mt < 4; mt++) {
                int m = mt * 16 + l16;
                a[mt] = *(const bf16x8*)(sF1 + m * 128 + ((kt * 64 + quad * 16) ^ ((m & 7) << 4)));
            }
            #pragma unroll
            for (int j = 0; j < 2; j++) {
                int n2 = (wave * 2 + j) * 16 + l16;
                bf16x8 b = *(const bf16x8*)(W2T + n2 * 64 + kt * 32 + quad * 8);
                #pragma unroll
                for (int mt = 0; mt < 4; mt++)
                    acc2[j][mt] = __builtin_amdgcn_mfma_f32_16x16x32_bf16(a[mt], b, acc2[j][mt], 0, 0, 0);
            }
        }
        // write feat2 into concat A-tile (k = 128 + n2 -> byte 256 + 2*n2, swizzled)
        #pragma unroll
        for (int j = 0; j < 2; j++) {
            int n2 = (wave * 2 + j) * 16 + l16;
            float bias = sb2v[n2];
            #pragma unroll
            for (int mt = 0; mt < 4; mt++)
                #pragma unroll
                for (int r = 0; r < 4; r++) {
                    int m = mt * 16 + quad * 4 + r;
                    float v = fmaxf(acc2[j][mt][r] + bias, 0.f);
                    *(unsigned short*)(sA + m * 512 + ((256 + 2 * n2) ^ ((m & 7) << 4))) = f2bf(v);
                }
        }
    }
    // store the gathered voxel features into concat A-tile (k 0..127 -> bytes 0..255)
    #pragma unroll
    for (int it = 0; it < 4; it++) {
        int i = tid + 256 * it;
        int m = i >> 4, c = i & 15;
        *(uint4*)(sA + m * 512 + ((c * 16) ^ ((m & 7) << 4))) = g[it];
    }
    __syncthreads();

    f32x4 acc[4][4];
    #pragma unroll
    for (int j = 0; j < 4; j++)
        #pragma unroll
        for (int mt = 0; mt < 4; mt++) acc[j][mt] = fzero;
    // GEMM3: [64][256] @ [256][256] (wave owns 4 n-tiles, all 4 m-tiles)
    #pragma unroll 1
    for (int kt = 0; kt < 8; kt++) {
        bf16x8 a[4];
        #pragma unroll
        for (int mt = 0; mt < 4; mt++) {
            int m = mt * 16 + l16;
            a[mt] = *(const bf16x8*)(sA + m * 512 + ((kt * 64 + quad * 16) ^ ((m & 7) << 4)));
        }
        #pragma unroll
        for (int j = 0; j < 4; j++) {
            int n = (wave * 4 + j) * 16 + l16;
            bf16x8 b = *(const bf16x8*)(W3T + n * 256 + kt * 32 + quad * 8);
            #pragma unroll
            for (int mt = 0; mt < 4; mt++)
                acc[j][mt] = __builtin_amdgcn_mfma_f32_16x16x32_bf16(a[mt], b, acc[j][mt], 0, 0, 0);
        }
    }
    __syncthreads();
    // feat4 (bias+relu) into sA, A-layout for GEMM4
    #pragma unroll
    for (int j = 0; j < 4; j++) {
        int n = (wave * 4 + j) * 16 + l16;
        float bias = sb3[n];
        #pragma unroll
        for (int mt = 0; mt < 4; mt++)
            #pragma unroll
            for (int r = 0; r < 4; r++) {
                int m = mt * 16 + quad * 4 + r;
                float v = fmaxf(acc[j][mt][r] + bias, 0.f);
                *(unsigned short*)(sA + m * 512 + ((2 * n) ^ ((m & 7) << 4))) = f2bf(v);
            }
    }
    __syncthreads();
    #pragma unroll
    for (int j = 0; j < 4; j++)
        #pragma unroll
        for (int mt = 0; mt < 4; mt++) acc[j][mt] = fzero;
    // GEMM4: [64][256] @ [256][256]
    #pragma unroll 1
    for (int kt = 0; kt < 8; kt++) {
        bf16x8 a[4];
        #pragma unroll
        for (int mt = 0; mt < 4; mt++) {
            int m = mt * 16 + l16;
            a[mt] = *(const bf16x8*)(sA + m * 512 + ((kt * 64 + quad * 16) ^ ((m & 7) << 4)));
        }
        #pragma unroll
        for (int j = 0; j < 4; j++) {
            int n = (wave * 4 + j) * 16 + l16;
            bf16x8 b = *(const bf16x8*)(W4T + n * 256 + kt * 32 + quad * 8);
            #pragma unroll
            for (int mt = 0; mt < 4; mt++)
                acc[j][mt] = __builtin_amdgcn_mfma_f32_16x16x32_bf16(a[mt], b, acc[j][mt], 0, 0, 0);
        }
    }
    // feat5 (bias+relu) -> scatter max into vox2acc (= d_out)
    #pragma unroll
    for (int j = 0; j < 4; j++) {
        int n = (wave * 4 + j) * 16 + l16;
        float bias = sb4[n];
        #pragma unroll
        for (int mt = 0; mt < 4; mt++)
            #pragma unroll
            for (int r = 0; r < 4; r++) {
                int m = mt * 16 + quad * 4 + r;
                int pt = pbase + m;
                if (pt < N_PTS) {
                    float v = fmaxf(acc[j][mt][r] + bias, 0.f);
                    atomicMax(vox2acc + (size_t)sidx[m] * 256 + n,
                              __float_as_uint(v) & 0x7fffffffu);
                }
            }
    }
}

// ---------------------------------------------------------------------------
// Voxel MLP: out = relu(in @ W + b); in fp32 [V][K], W as WT bf16 [NOUT][K].
// 64 voxels / block, 4 waves. Safe for in == out (rows staged to LDS first).
// ---------------------------------------------------------------------------
template <int K, int NOUT, bool OUTBF>
__global__ __launch_bounds__(256) void kvox(
    const float* __restrict__ in, const unsigned short* __restrict__ WT,
    const float* __restrict__ bias, void* __restrict__ outp)
{
    __shared__ __align__(16) char sA[64 * K * 2];
    __shared__ float sb[NOUT];
    const f32x4 fzero = {0.f, 0.f, 0.f, 0.f};
    int tid = threadIdx.x;
    int vb = blockIdx.x * 64;
    #pragma unroll
    for (int i = tid; i < NOUT; i += 256) sb[i] = bias[i];
    constexpr int KQ = K / 4;
    #pragma unroll 1
    for (int i = tid; i < 64 * KQ; i += 256) {
        int m = i / KQ, kq = i % KQ;
        float4 f = ((const float4*)(in + (size_t)(vb + m) * K))[kq];
        uint2 p;
        p.x = (unsigned)f2bf(f.x) | ((unsigned)f2bf(f.y) << 16);
        p.y = (unsigned)f2bf(f.z) | ((unsigned)f2bf(f.w) << 16);
        *(uint2*)(sA + m * (2 * K) + ((8 * kq) ^ ((m & 7) << 4))) = p;
    }
    __syncthreads();
    int wave = tid >> 6, lane = tid & 63, quad = lane >> 4, l16 = lane & 15;
    constexpr int NTW = NOUT / 64;
    f32x4 acc[NTW][4];
    #pragma unroll
    for (int j = 0; j < NTW; j++)
        #pragma unroll
        for (int mt = 0; mt < 4; mt++) acc[j][mt] = fzero;
    #pragma unroll 1
    for (int kt = 0; kt < K / 32; kt++) {
        bf16x8 a[4];
        #pragma unroll
        for (int mt = 0; mt < 4; mt++) {
            int m = mt * 16 + l16;
            a[mt] = *(const bf16x8*)(sA + m * (2 * K) + ((kt * 64 + quad * 16) ^ ((m & 7) << 4)));
        }
        #pragma unroll
        for (int j = 0; j < NTW; j++) {
            int n = (wave * NTW + j) * 16 + l16;
            bf16x8 b = *(const bf16x8*)(WT + n * K + kt * 32 + quad * 8);
            #pragma unroll
            for (int mt = 0; mt < 4; mt++)
                acc[j][mt] = __builtin_amdgcn_mfma_f32_16x16x32_bf16(a[mt], b, acc[j][mt], 0, 0, 0);
        }
    }
    #pragma unroll
    for (int j = 0; j < NTW; j++) {
        int n = (wave * NTW + j) * 16 + l16;
        float bi = sb[n];
        #pragma unroll
        for (int mt = 0; mt < 4; mt++)
            #pragma unroll
            for (int r = 0; r < 4; r++) {
                int m = mt * 16 + quad * 4 + r;
                float v = fmaxf(acc[j][mt][r] + bi, 0.f);
                if (OUTBF) ((unsigned short*)outp)[(size_t)(vb + m) * NOUT + n] = f2bf(v);
                else       ((float*)outp)[(size_t)(vb + m) * NOUT + n] = v;
            }
    }
}

extern "C" void kernel_launch(void* const* d_in, const int* in_sizes, int n_in,
                              void* d_out, int out_size, void* d_ws, size_t ws_size,
                              hipStream_t stream) {
    const float* inp  = (const float*)d_in[0];
    const int*   idx  = (const int*)d_in[1];
    const float* W1   = (const float*)d_in[2];
    const float* b1   = (const float*)d_in[3];
    const float* W2   = (const float*)d_in[4];
    const float* b2   = (const float*)d_in[5];
    const float* Wv1  = (const float*)d_in[6];
    const float* bv1  = (const float*)d_in[7];
    const float* W3   = (const float*)d_in[8];
    const float* b3   = (const float*)d_in[9];
    const float* W4   = (const float*)d_in[10];
    const float* b4   = (const float*)d_in[11];
    const float* Wv2  = (const float*)d_in[12];
    const float* bv2  = (const float*)d_in[13];

    // workspace layout — total ~48.5 MB (vox2acc lives in d_out)
    char* ws = (char*)d_ws;
    size_t off = 0;
    unsigned int*   vox1acc = (unsigned int*)(ws + off);   off += (size_t)NVOX * 128 * 4;  // 32 MB
    unsigned short* vox1out = (unsigned short*)(ws + off); off += (size_t)NVOX * 128 * 2;  // 16 MB
    unsigned short* W1T     = (unsigned short*)(ws + off); off += 64 * 32 * 2;
    unsigned short* W2T     = (unsigned short*)(ws + off); off += 128 * 64 * 2;
    unsigned short* Wv1T    = (unsigned short*)(ws + off); off += 128 * 128 * 2;
    unsigned short* W3T     = (unsigned short*)(ws + off); off += 256 * 256 * 2;
    unsigned short* W4T     = (unsigned short*)(ws + off); off += 256 * 256 * 2;
    unsigned short* Wv2T    = (unsigned short*)(ws + off); off += 256 * 256 * 2;

    unsigned int* vox2acc = (unsigned int*)d_out;          // [V][256] — aliased with output

    hipMemsetAsync(vox1acc, 0, (size_t)NVOX * 128 * 4, stream);
    hipMemsetAsync(vox2acc, 0, (size_t)NVOX * 256 * 4, stream);

    prep_w1T<<<(64 * 32 + 255) / 256, 256, 0, stream>>>(W1, W1T);
    prep_wT<<<(128 * 64 + 255) / 256, 256, 0, stream>>>(W2, W2T, 64, 128);
    prep_wT<<<(128 * 128 + 255) / 256, 256, 0, stream>>>(Wv1, Wv1T, 128, 128);
    prep_wT<<<(256 * 256 + 255) / 256, 256, 0, stream>>>(W3, W3T, 256, 256);
    prep_wT<<<(256 * 256 + 255) / 256, 256, 0, stream>>>(W4, W4T, 256, 256);
    prep_wT<<<(256 * 256 + 255) / 256, 256, 0, stream>>>(Wv2, Wv2T, 256, 256);

    k1_points<<<(N_PTS + 255) / 256, 256, 0, stream>>>(inp, idx, W1T, b1, W2T, b2, vox1acc);
    kvox<128, 128, true><<<NVOX / 64, 256, 0, stream>>>((const float*)vox1acc, Wv1T, bv1,
                                                        (void*)vox1out);
    k3_heavy<<<(N_PTS + 63) / 64, 256, 0, stream>>>(inp, idx, W1T, b1, W2T, b2, vox1out,
                                                    W3T, b3, W4T, b4, vox2acc);
    kvox<256, 256, false><<<NVOX / 64, 256, 0, stream>>>((const float*)vox2acc, Wv2T, bv2,
                                                         d_out);
}

// Round 3
// 727.068 us; speedup vs baseline: 1.0927x; 1.0927x over previous
//
#include <hip/hip_runtime.h>
#include <hip/hip_bf16.h>
#include <stdint.h>

#define N_PTS 500000
#define NVOX  65536
#define K1_TILES ((N_PTS + 127) / 128)   // 3907
#define K3_TILES ((N_PTS + 63) / 64)     // 7813

typedef __attribute__((ext_vector_type(8))) short bf16x8;   // 8 x bf16 (4 VGPRs)
typedef __attribute__((ext_vector_type(4))) float f32x4;    // MFMA accumulator

__device__ inline unsigned short f2bf(float f) {
    union { float f; unsigned int u; } v; v.f = f;
    unsigned int r = v.u + 0x7FFFu + ((v.u >> 16) & 1u);   // RNE
    return (unsigned short)(r >> 16);
}
__device__ inline float bf2f(unsigned short h) {
    return __uint_as_float((unsigned int)h << 16);
}

// transpose [K][Nn] fp32 -> [Nn][K] bf16
__global__ void prep_wT(const float* __restrict__ src, unsigned short* __restrict__ dst,
                        int K, int Nn) {
    int i = blockIdx.x * 256 + threadIdx.x;
    if (i >= K * Nn) return;
    int n = i / K, k = i % K;
    dst[i] = f2bf(src[k * Nn + n]);
}

// W1 [6][64] -> [64][32] bf16, zero-padded in k
__global__ void prep_w1T(const float* __restrict__ src, unsigned short* __restrict__ dst) {
    int i = blockIdx.x * 256 + threadIdx.x;
    if (i >= 64 * 32) return;
    int n = i >> 5, k = i & 31;
    dst[i] = (k < 6) ? f2bf(src[k * 64 + n]) : (unsigned short)0;
}

// ------------------------- counting sort by voxel --------------------------
__global__ void s_hist(const int* __restrict__ idx, unsigned int* __restrict__ counts) {
    int p = blockIdx.x * 256 + threadIdx.x;
    if (p < N_PTS) atomicAdd(&counts[idx[p]], 1u);
}

// exclusive scan of counts[65536] -> cursor[65536]; single block of 1024 threads
__global__ __launch_bounds__(1024) void s_scan(const unsigned int* __restrict__ counts,
                                               unsigned int* __restrict__ cursor) {
    __shared__ unsigned int sPart[1024];
    int t = threadIdx.x;
    unsigned int sum = 0;
    #pragma unroll 8
    for (int i = 0; i < 64; i++) sum += counts[t * 64 + i];
    sPart[t] = sum;
    __syncthreads();
    for (int d = 1; d < 1024; d <<= 1) {
        unsigned int add = (t >= d) ? sPart[t - d] : 0u;
        __syncthreads();
        sPart[t] += add;
        __syncthreads();
    }
    unsigned int run = (t == 0) ? 0u : sPart[t - 1];
    #pragma unroll 8
    for (int i = 0; i < 64; i++) {
        cursor[t * 64 + i] = run;
        run += counts[t * 64 + i];
    }
}

__global__ void s_scatter(const int* __restrict__ idx, unsigned int* __restrict__ cursor,
                          int* __restrict__ order, int* __restrict__ svox) {
    int p = blockIdx.x * 256 + threadIdx.x;
    if (p < N_PTS) {
        int v = idx[p];
        unsigned int pos = atomicAdd(&cursor[v], 1u);
        order[pos] = p;
        svox[pos] = v;
    }
}

// ---------------------------------------------------------------------------
// K1 (sorted): per 128-sorted-point tile: feat1 = relu(x@W1+b1),
// feat2 = relu(feat1@W2+b2) via MFMA; segmented max over voxel runs in LDS,
// ONE atomicMax per (segment,col) -> vox1acc.
// LDS overlay in sBuf[32K]: sIn [0,8K) rows 64B; sF1 [8K,24K) rows 128B;
// sF2 [0,32K) rows 256B (written only after all sIn/sF1 reads complete).
// ---------------------------------------------------------------------------
__global__ __launch_bounds__(256) void k1_points(
    const float* __restrict__ inp,
    const int* __restrict__ order, const int* __restrict__ svox,
    const unsigned short* __restrict__ W1T, const float* __restrict__ b1,
    const unsigned short* __restrict__ W2T, const float* __restrict__ b2,
    unsigned int* __restrict__ vox1acc)      // [V][128] fp32-as-uint (zeroed)
{
    __shared__ __align__(16) char sBuf[32 * 1024];
    __shared__ float sb1[64];
    __shared__ float sb2[128];
    __shared__ int   sVox[128];
    char* sIn = sBuf;                // [128][32] bf16, row 64B,  swz (m&3)<<4
    char* sF1 = sBuf + 8 * 1024;     // [128][64] bf16, row 128B, swz (m&7)<<4
    char* sF2 = sBuf;                // [128][128] bf16, row 256B, swz (m&7)<<4
    const f32x4 fzero = {0.f, 0.f, 0.f, 0.f};
    int tid = threadIdx.x;
    int pbase = blockIdx.x * 128;
    if (tid < 64)       sb1[tid] = b1[tid];
    else if (tid < 192) sb2[tid - 64] = b2[tid - 64];
    if (tid < 128) {
        int i = pbase + tid;
        int pt = -1, v = -1;
        if (i < N_PTS) { pt = order[i]; v = svox[i]; }
        sVox[tid] = v;
        uint4 g0 = {0u, 0u, 0u, 0u};
        if (pt >= 0) {
            const float* x = inp + (size_t)pt * 6;
            g0.x = (unsigned)f2bf(x[0]) | ((unsigned)f2bf(x[1]) << 16);
            g0.y = (unsigned)f2bf(x[2]) | ((unsigned)f2bf(x[3]) << 16);
            g0.z = (unsigned)f2bf(x[4]) | ((unsigned)f2bf(x[5]) << 16);
        }
        int swz = (tid & 3) << 4;
        char* row = sIn + tid * 64;
        uint4 z = {0u, 0u, 0u, 0u};
        *(uint4*)(row + (0  ^ swz)) = g0;
        *(uint4*)(row + (16 ^ swz)) = z;
        *(uint4*)(row + (32 ^ swz)) = z;
        *(uint4*)(row + (48 ^ swz)) = z;
    }
    __syncthreads();
    int wave = tid >> 6, lane = tid & 63, quad = lane >> 4, l16 = lane & 15;

    // GEMM1: [128][32]@[32][64]; wave owns n-tile `wave`, all 8 m-tiles
    {
        f32x4 acc1[8];
        #pragma unroll
        for (int mt = 0; mt < 8; mt++) acc1[mt] = fzero;
        bf16x8 a[8];
        #pragma unroll
        for (int mt = 0; mt < 8; mt++) {
            int m = mt * 16 + l16;
            a[mt] = *(const bf16x8*)(sIn + m * 64 + ((quad * 16) ^ ((m & 3) << 4)));
        }
        int n = wave * 16 + l16;
        bf16x8 b = *(const bf16x8*)(W1T + n * 32 + quad * 8);
        #pragma unroll
        for (int mt = 0; mt < 8; mt++)
            acc1[mt] = __builtin_amdgcn_mfma_f32_16x16x32_bf16(a[mt], b, acc1[mt], 0, 0, 0);
        float bias = sb1[n];
        #pragma unroll
        for (int mt = 0; mt < 8; mt++)
            #pragma unroll
            for (int r = 0; r < 4; r++) {
                int m = mt * 16 + quad * 4 + r;
                float v = fmaxf(acc1[mt][r] + bias, 0.f);
                *(unsigned short*)(sF1 + m * 128 + ((2 * n) ^ ((m & 7) << 4))) = f2bf(v);
            }
    }
    __syncthreads();
    // GEMM2: [128][64]@[64][128]; wave owns n-tiles 2w,2w+1, all 8 m-tiles
    f32x4 acc2[2][8];
    #pragma unroll
    for (int j = 0; j < 2; j++)
        #pragma unroll
        for (int mt = 0; mt < 8; mt++) acc2[j][mt] = fzero;
    #pragma unroll
    for (int kt = 0; kt < 2; kt++) {
        bf16x8 a[8];
        #pragma unroll
        for (int mt = 0; mt < 8; mt++) {
            int m = mt * 16 + l16;
            a[mt] = *(const bf16x8*)(sF1 + m * 128 + ((kt * 64 + quad * 16) ^ ((m & 7) << 4)));
        }
        #pragma unroll
        for (int j = 0; j < 2; j++) {
            int n = (wave * 2 + j) * 16 + l16;
            bf16x8 b = *(const bf16x8*)(W2T + n * 64 + kt * 32 + quad * 8);
            #pragma unroll
            for (int mt = 0; mt < 8; mt++)
                acc2[j][mt] = __builtin_amdgcn_mfma_f32_16x16x32_bf16(a[mt], b, acc2[j][mt], 0, 0, 0);
        }
    }
    __syncthreads();   // all sIn/sF1 reads done before sF2 overwrite
    #pragma unroll
    for (int j = 0; j < 2; j++) {
        int n = (wave * 2 + j) * 16 + l16;
        float bias = sb2[n];
        #pragma unroll
        for (int mt = 0; mt < 8; mt++)
            #pragma unroll
            for (int r = 0; r < 4; r++) {
                int m = mt * 16 + quad * 4 + r;
                float v = fmaxf(acc2[j][mt][r] + bias, 0.f);
                *(unsigned short*)(sF2 + m * 256 + ((2 * n) ^ ((m & 7) << 4))) = f2bf(v);
            }
    }
    __syncthreads();
    // segmented max walk: col = tid&127, half = tid>>7 walks 64 rows
    {
        int c = tid & 127, r0 = (tid >> 7) * 64;
        int cur = -1; float vmax = 0.f;
        for (int r = r0; r < r0 + 64; r++) {
            int v = sVox[r];
            float f = bf2f(*(const unsigned short*)(sF2 + r * 256 + ((2 * c) ^ ((r & 7) << 4))));
            if (v != cur) {
                if (cur >= 0)
                    atomicMax(vox1acc + (size_t)cur * 128 + c, __float_as_uint(vmax));
                cur = v; vmax = f;
            } else vmax = fmaxf(vmax, f);
        }
        if (cur >= 0)
            atomicMax(vox1acc + (size_t)cur * 128 + c, __float_as_uint(vmax));
    }
}

// ---------------------------------------------------------------------------
// K3 (sorted): per 64-sorted-point tile: recompute feat1/feat2, concat with
// gathered voxel features (now voxel-contiguous -> cache-friendly), two
// 256x256 MFMA layers, segmented max -> one atomicMax per (segment,col).
// ---------------------------------------------------------------------------
__global__ __launch_bounds__(256) void k3_heavy(
    const float* __restrict__ inp,
    const int* __restrict__ order, const int* __restrict__ svox,
    const unsigned short* __restrict__ W1T, const float* __restrict__ b1,
    const unsigned short* __restrict__ W2T, const float* __restrict__ b2,
    const unsigned short* __restrict__ vox1out,  // [V][128] bf16
    const unsigned short* __restrict__ W3T, const float* __restrict__ b3,
    const unsigned short* __restrict__ W4T, const float* __restrict__ b4,
    unsigned int* __restrict__ vox2acc)          // [V][256] fp32-as-uint (zeroed)
{
    __shared__ __align__(16) char sA[64 * 512];   // [64][256] bf16 concat/feat4/feat5
    __shared__ __align__(16) char sF1[64 * 128];  // [64][64]  bf16 feat1
    __shared__ __align__(16) char sIn[64 * 64];   // [64][32]  bf16 input (padded)
    __shared__ float sb1v[64];
    __shared__ float sb2v[128];
    __shared__ float sb3[256];
    __shared__ float sb4[256];
    __shared__ int   sidx[64];
    const f32x4 fzero = {0.f, 0.f, 0.f, 0.f};
    int tid = threadIdx.x;
    int pbase = blockIdx.x * 64;
    sb3[tid] = b3[tid];
    sb4[tid] = b4[tid];
    if (tid < 64)  sb1v[tid] = b1[tid];
    if (tid < 128) sb2v[tid] = b2[tid];
    if (tid < 64) {
        int i = pbase + tid;
        int pt = -1, v = -1;
        if (i < N_PTS) { pt = order[i]; v = svox[i]; }
        sidx[tid] = v;
        uint4 g0 = {0u, 0u, 0u, 0u};
        if (pt >= 0) {
            const float* x = inp + (size_t)pt * 6;
            g0.x = (unsigned)f2bf(x[0]) | ((unsigned)f2bf(x[1]) << 16);
            g0.y = (unsigned)f2bf(x[2]) | ((unsigned)f2bf(x[3]) << 16);
            g0.z = (unsigned)f2bf(x[4]) | ((unsigned)f2bf(x[5]) << 16);
        }
        int swz2 = (tid & 3) << 4;
        char* row = sIn + tid * 64;
        uint4 z = {0u, 0u, 0u, 0u};
        *(uint4*)(row + (0  ^ swz2)) = g0;
        *(uint4*)(row + (16 ^ swz2)) = z;
        *(uint4*)(row + (32 ^ swz2)) = z;
        *(uint4*)(row + (48 ^ swz2)) = z;
    }
    __syncthreads();
    int wave = tid >> 6, lane = tid & 63, quad = lane >> 4, l16 = lane & 15;

    // gather voxel features early (sorted -> heavily deduped, L1/L2 hits)
    uint4 g[4];
    #pragma unroll
    for (int it = 0; it < 4; it++) {
        int i = tid + 256 * it;
        int m = i >> 4, c = i & 15;
        int vv = sidx[m];
        uint4 val = {0u, 0u, 0u, 0u};
        if (vv >= 0)
            val = ((const uint4*)(vox1out + (size_t)vv * 128))[c];
        g[it] = val;
    }

    // small GEMM1: feat1 = relu([64][32] @ [32][64] + b1)
    {
        f32x4 acc1[4];
        #pragma unroll
        for (int mt = 0; mt < 4; mt++) acc1[mt] = fzero;
        bf16x8 a[4];
        #pragma unroll
        for (int mt = 0; mt < 4; mt++) {
            int m = mt * 16 + l16;
            a[mt] = *(const bf16x8*)(sIn + m * 64 + ((quad * 16) ^ ((m & 3) << 4)));
        }
        int n = wave * 16 + l16;
        bf16x8 b = *(const bf16x8*)(W1T + n * 32 + quad * 8);
        #pragma unroll
        for (int mt = 0; mt < 4; mt++)
            acc1[mt] = __builtin_amdgcn_mfma_f32_16x16x32_bf16(a[mt], b, acc1[mt], 0, 0, 0);
        float bias = sb1v[n];
        #pragma unroll
        for (int mt = 0; mt < 4; mt++)
            #pragma unroll
            for (int r = 0; r < 4; r++) {
                int m = mt * 16 + quad * 4 + r;
                float v = fmaxf(acc1[mt][r] + bias, 0.f);
                *(unsigned short*)(sF1 + m * 128 + ((2 * n) ^ ((m & 7) << 4))) = f2bf(v);
            }
    }
    __syncthreads();
    // small GEMM2: feat2 = relu([64][64] @ [64][128] + b2) -> concat k=128..255
    {
        f32x4 acc2[2][4];
        #pragma unroll
        for (int j = 0; j < 2; j++)
            #pragma unroll
            for (int mt = 0; mt < 4; mt++) acc2[j][mt] = fzero;
        #pragma unroll
        for (int kt = 0; kt < 2; kt++) {
            bf16x8 a[4];
            #pragma unroll
            for (int mt = 0; mt < 4; mt++) {
                int m = mt * 16 + l16;
                a[mt] = *(const bf16x8*)(sF1 + m * 128 + ((kt * 64 + quad * 16) ^ ((m & 7) << 4)));
            }
            #pragma unroll
            for (int j = 0; j < 2; j++) {
                int n2 = (wave * 2 + j) * 16 + l16;
                bf16x8 b = *(const bf16x8*)(W2T + n2 * 64 + kt * 32 + quad * 8);
                #pragma unroll
                for (int mt = 0; mt < 4; mt++)
                    acc2[j][mt] = __builtin_amdgcn_mfma_f32_16x16x32_bf16(a[mt], b, acc2[j][mt], 0, 0, 0);
            }
        }
        #pragma unroll
        for (int j = 0; j < 2; j++) {
            int n2 = (wave * 2 + j) * 16 + l16;
            float bias = sb2v[n2];
            #pragma unroll
            for (int mt = 0; mt < 4; mt++)
                #pragma unroll
                for (int r = 0; r < 4; r++) {
                    int m = mt * 16 + quad * 4 + r;
                    float v = fmaxf(acc2[j][mt][r] + bias, 0.f);
                    *(unsigned short*)(sA + m * 512 + ((256 + 2 * n2) ^ ((m & 7) << 4))) = f2bf(v);
                }
        }
    }
    // gathered voxel features -> concat k=0..127
    #pragma unroll
    for (int it = 0; it < 4; it++) {
        int i = tid + 256 * it;
        int m = i >> 4, c = i & 15;
        *(uint4*)(sA + m * 512 + ((c * 16) ^ ((m & 7) << 4))) = g[it];
    }
    __syncthreads();

    f32x4 acc[4][4];
    #pragma unroll
    for (int j = 0; j < 4; j++)
        #pragma unroll
        for (int mt = 0; mt < 4; mt++) acc[j][mt] = fzero;
    // GEMM3: [64][256] @ [256][256]
    #pragma unroll 1
    for (int kt = 0; kt < 8; kt++) {
        bf16x8 a[4];
        #pragma unroll
        for (int mt = 0; mt < 4; mt++) {
            int m = mt * 16 + l16;
            a[mt] = *(const bf16x8*)(sA + m * 512 + ((kt * 64 + quad * 16) ^ ((m & 7) << 4)));
        }
        #pragma unroll
        for (int j = 0; j < 4; j++) {
            int n = (wave * 4 + j) * 16 + l16;
            bf16x8 b = *(const bf16x8*)(W3T + n * 256 + kt * 32 + quad * 8);
            #pragma unroll
            for (int mt = 0; mt < 4; mt++)
                acc[j][mt] = __builtin_amdgcn_mfma_f32_16x16x32_bf16(a[mt], b, acc[j][mt], 0, 0, 0);
        }
    }
    __syncthreads();
    // feat4 -> sA (A-layout)
    #pragma unroll
    for (int j = 0; j < 4; j++) {
        int n = (wave * 4 + j) * 16 + l16;
        float bias = sb3[n];
        #pragma unroll
        for (int mt = 0; mt < 4; mt++)
            #pragma unroll
            for (int r = 0; r < 4; r++) {
                int m = mt * 16 + quad * 4 + r;
                float v = fmaxf(acc[j][mt][r] + bias, 0.f);
                *(unsigned short*)(sA + m * 512 + ((2 * n) ^ ((m & 7) << 4))) = f2bf(v);
            }
    }
    __syncthreads();
    #pragma unroll
    for (int j = 0; j < 4; j++)
        #pragma unroll
        for (int mt = 0; mt < 4; mt++) acc[j][mt] = fzero;
    // GEMM4: [64][256] @ [256][256]
    #pragma unroll 1
    for (int kt = 0; kt < 8; kt++) {
        bf16x8 a[4];
        #pragma unroll
        for (int mt = 0; mt < 4; mt++) {
            int m = mt * 16 + l16;
            a[mt] = *(const bf16x8*)(sA + m * 512 + ((kt * 64 + quad * 16) ^ ((m & 7) << 4)));
        }
        #pragma unroll
        for (int j = 0; j < 4; j++) {
            int n = (wave * 4 + j) * 16 + l16;
            bf16x8 b = *(const bf16x8*)(W4T + n * 256 + kt * 32 + quad * 8);
            #pragma unroll
            for (int mt = 0; mt < 4; mt++)
                acc[j][mt] = __builtin_amdgcn_mfma_f32_16x16x32_bf16(a[mt], b, acc[j][mt], 0, 0, 0);
        }
    }
    __syncthreads();   // all feat4 reads done before feat5 overwrite
    // feat5 -> sA
    #pragma unroll
    for (int j = 0; j < 4; j++) {
        int n = (wave * 4 + j) * 16 + l16;
        float bias = sb4[n];
        #pragma unroll
        for (int mt = 0; mt < 4; mt++)
            #pragma unroll
            for (int r = 0; r < 4; r++) {
                int m = mt * 16 + quad * 4 + r;
                float v = fmaxf(acc[j][mt][r] + bias, 0.f);
                *(unsigned short*)(sA + m * 512 + ((2 * n) ^ ((m & 7) << 4))) = f2bf(v);
            }
    }
    __syncthreads();
    // segmented max walk: col = tid (256 cols), 64 rows
    {
        int c = tid;
        int cur = -1; float vmax = 0.f;
        for (int r = 0; r < 64; r++) {
            int v = sidx[r];
            float f = bf2f(*(const unsigned short*)(sA + r * 512 + ((2 * c) ^ ((r & 7) << 4))));
            if (v != cur) {
                if (cur >= 0)
                    atomicMax(vox2acc + (size_t)cur * 256 + c, __float_as_uint(vmax));
                cur = v; vmax = f;
            } else vmax = fmaxf(vmax, f);
        }
        if (cur >= 0)
            atomicMax(vox2acc + (size_t)cur * 256 + c, __float_as_uint(vmax));
    }
}

// ---------------------------------------------------------------------------
// Voxel MLP: out = relu(in @ W + b); safe for in == out (rows staged to LDS).
// ---------------------------------------------------------------------------
template <int K, int NOUT, bool OUTBF>
__global__ __launch_bounds__(256) void kvox(
    const float* __restrict__ in, const unsigned short* __restrict__ WT,
    const float* __restrict__ bias, void* __restrict__ outp)
{
    __shared__ __align__(16) char sA[64 * K * 2];
    __shared__ float sb[NOUT];
    const f32x4 fzero = {0.f, 0.f, 0.f, 0.f};
    int tid = threadIdx.x;
    int vb = blockIdx.x * 64;
    #pragma unroll
    for (int i = tid; i < NOUT; i += 256) sb[i] = bias[i];
    constexpr int KQ = K / 4;
    #pragma unroll 1
    for (int i = tid; i < 64 * KQ; i += 256) {
        int m = i / KQ, kq = i % KQ;
        float4 f = ((const float4*)(in + (size_t)(vb + m) * K))[kq];
        uint2 p;
        p.x = (unsigned)f2bf(f.x) | ((unsigned)f2bf(f.y) << 16);
        p.y = (unsigned)f2bf(f.z) | ((unsigned)f2bf(f.w) << 16);
        *(uint2*)(sA + m * (2 * K) + ((8 * kq) ^ ((m & 7) << 4))) = p;
    }
    __syncthreads();
    int wave = tid >> 6, lane = tid & 63, quad = lane >> 4, l16 = lane & 15;
    constexpr int NTW = NOUT / 64;
    f32x4 acc[NTW][4];
    #pragma unroll
    for (int j = 0; j < NTW; j++)
        #pragma unroll
        for (int mt = 0; mt < 4; mt++) acc[j][mt] = fzero;
    #pragma unroll 1
    for (int kt = 0; kt < K / 32; kt++) {
        bf16x8 a[4];
        #pragma unroll
        for (int mt = 0; mt < 4; mt++) {
            int m = mt * 16 + l16;
            a[mt] = *(const bf16x8*)(sA + m * (2 * K) + ((kt * 64 + quad * 16) ^ ((m & 7) << 4)));
        }
        #pragma unroll
        for (int j = 0; j < NTW; j++) {
            int n = (wave * NTW + j) * 16 + l16;
            bf16x8 b = *(const bf16x8*)(WT + n * K + kt * 32 + quad * 8);
            #pragma unroll
            for (int mt = 0; mt < 4; mt++)
                acc[j][mt] = __builtin_amdgcn_mfma_f32_16x16x32_bf16(a[mt], b, acc[j][mt], 0, 0, 0);
        }
    }
    #pragma unroll
    for (int j = 0; j < NTW; j++) {
        int n = (wave * NTW + j) * 16 + l16;
        float bi = sb[n];
        #pragma unroll
        for (int mt = 0; mt < 4; mt++)
            #pragma unroll
            for (int r = 0; r < 4; r++) {
                int m = mt * 16 + quad * 4 + r;
                float v = fmaxf(acc[j][mt][r] + bi, 0.f);
                if (OUTBF) ((unsigned short*)outp)[(size_t)(vb + m) * NOUT + n] = f2bf(v);
                else       ((float*)outp)[(size_t)(vb + m) * NOUT + n] = v;
            }
    }
}

extern "C" void kernel_launch(void* const* d_in, const int* in_sizes, int n_in,
                              void* d_out, int out_size, void* d_ws, size_t ws_size,
                              hipStream_t stream) {
    const float* inp  = (const float*)d_in[0];
    const int*   idx  = (const int*)d_in[1];
    const float* W1   = (const float*)d_in[2];
    const float* b1   = (const float*)d_in[3];
    const float* W2   = (const float*)d_in[4];
    const float* b2   = (const float*)d_in[5];
    const float* Wv1  = (const float*)d_in[6];
    const float* bv1  = (const float*)d_in[7];
    const float* W3   = (const float*)d_in[8];
    const float* b3   = (const float*)d_in[9];
    const float* W4   = (const float*)d_in[10];
    const float* b4   = (const float*)d_in[11];
    const float* Wv2  = (const float*)d_in[12];
    const float* bv2  = (const float*)d_in[13];

    // workspace layout — ~52.5 MB (vox2acc lives in d_out)
    char* ws = (char*)d_ws;
    size_t off = 0;
    unsigned int*   vox1acc = (unsigned int*)(ws + off);   off += (size_t)NVOX * 128 * 4;  // 32 MB
    unsigned int*   counts  = (unsigned int*)(ws + off);   off += (size_t)NVOX * 4;        // 256 KB (memset w/ vox1acc)
    unsigned int*   cursor  = (unsigned int*)(ws + off);   off += (size_t)NVOX * 4;        // fully written by s_scan
    unsigned short* vox1out = (unsigned short*)(ws + off); off += (size_t)NVOX * 128 * 2;  // 16 MB
    int*            order   = (int*)(ws + off);            off += (size_t)N_PTS * 4;       // 2 MB
    int*            svox    = (int*)(ws + off);            off += (size_t)N_PTS * 4;       // 2 MB
    unsigned short* W1T     = (unsigned short*)(ws + off); off += 64 * 32 * 2;
    unsigned short* W2T     = (unsigned short*)(ws + off); off += 128 * 64 * 2;
    unsigned short* Wv1T    = (unsigned short*)(ws + off); off += 128 * 128 * 2;
    unsigned short* W3T     = (unsigned short*)(ws + off); off += 256 * 256 * 2;
    unsigned short* W4T     = (unsigned short*)(ws + off); off += 256 * 256 * 2;
    unsigned short* Wv2T    = (unsigned short*)(ws + off); off += 256 * 256 * 2;

    unsigned int* vox2acc = (unsigned int*)d_out;          // [V][256] — aliased with output

    hipMemsetAsync(vox1acc, 0, (size_t)NVOX * 128 * 4 + (size_t)NVOX * 4, stream); // vox1acc + counts
    hipMemsetAsync(vox2acc, 0, (size_t)NVOX * 256 * 4, stream);

    prep_w1T<<<(64 * 32 + 255) / 256, 256, 0, stream>>>(W1, W1T);
    prep_wT<<<(128 * 64 + 255) / 256, 256, 0, stream>>>(W2, W2T, 64, 128);
    prep_wT<<<(128 * 128 + 255) / 256, 256, 0, stream>>>(Wv1, Wv1T, 128, 128);
    prep_wT<<<(256 * 256 + 255) / 256, 256, 0, stream>>>(W3, W3T, 256, 256);
    prep_wT<<<(256 * 256 + 255) / 256, 256, 0, stream>>>(W4, W4T, 256, 256);
    prep_wT<<<(256 * 256 + 255) / 256, 256, 0, stream>>>(Wv2, Wv2T, 256, 256);

    s_hist<<<(N_PTS + 255) / 256, 256, 0, stream>>>(idx, counts);
    s_scan<<<1, 1024, 0, stream>>>(counts, cursor);
    s_scatter<<<(N_PTS + 255) / 256, 256, 0, stream>>>(idx, cursor, order, svox);

    k1_points<<<K1_TILES, 256, 0, stream>>>(inp, order, svox, W1T, b1, W2T, b2, vox1acc);
    kvox<128, 128, true><<<NVOX / 64, 256, 0, stream>>>((const float*)vox1acc, Wv1T, bv1,
                                                        (void*)vox1out);
    k3_heavy<<<K3_TILES, 256, 0, stream>>>(inp, order, svox, W1T, b1, W2T, b2, vox1out,
                                           W3T, b3, W4T, b4, vox2acc);
    kvox<256, 256, false><<<NVOX / 64, 256, 0, stream>>>((const float*)vox2acc, Wv2T, bv2,
                                                         d_out);
}